// Round 4
// baseline (630.676 us; speedup 1.0000x reference)
//
#include <hip/hip_runtime.h>
#include <hip/hip_bf16.h>

#define N_NODES 50000
#define N_EDGES 250000
#define NHEAD   12
#define NH      (N_NODES * NHEAD)   /* 600000 rows of 64 */
#define ROW_TILES (NH / 16)         /* 37500 */

typedef __bf16 bf16_t;
typedef __bf16 bf16x8 __attribute__((ext_vector_type(8)));
typedef __bf16 bf16x4 __attribute__((ext_vector_type(4)));
typedef float  f32x4  __attribute__((ext_vector_type(4)));

__device__ __forceinline__ bf16x8 cvt8(f32x4 a, f32x4 b) {
    bf16x8 r;
    r[0] = (bf16_t)a[0]; r[1] = (bf16_t)a[1]; r[2] = (bf16_t)a[2]; r[3] = (bf16_t)a[3];
    r[4] = (bf16_t)b[0]; r[5] = (bf16_t)b[1]; r[6] = (bf16_t)b[2]; r[7] = (bf16_t)b[3];
    return r;
}

// ---------------- degree histogram + weight bf16 pre-conversion ----------------
// blocks 0..976: edge-degree atomics; blocks 977..992: convert wfc/wres to bf16.
__global__ __launch_bounds__(256) void k_deg_prep(
    const int* __restrict__ dst, int* __restrict__ deg,
    const float* __restrict__ wfc, const float* __restrict__ wres,
    bf16_t* __restrict__ wfb, bf16_t* __restrict__ wrb)
{
    int b = blockIdx.x;
    if (b < 977) {
        int i = b * 256 + threadIdx.x;
        if (i < N_EDGES) atomicAdd(&deg[dst[i]], 1);
    } else {
        int t = (b - 977) * 256 + threadIdx.x;   // 0..4095
        wfb[t] = (bf16_t)wfc[t];
        wrb[t] = (bf16_t)wres[t];
    }
}

// single block, 1024 threads, 52 nodes/thread; int4-vectorized loads.
__global__ __launch_bounds__(1024) void k_scan(const int* __restrict__ deg,
                                               int* __restrict__ rowptr,
                                               int* __restrict__ cursor) {
    __shared__ int s[1024];
    const int CH = 52;
    int t = threadIdx.x;
    int base = t * CH;
    int loc[CH];
    if (base + CH <= N_NODES) {
        const int4* p = reinterpret_cast<const int4*>(deg + base);
#pragma unroll
        for (int i = 0; i < CH / 4; ++i) {
            int4 q = p[i];
            loc[4 * i + 0] = q.x; loc[4 * i + 1] = q.y;
            loc[4 * i + 2] = q.z; loc[4 * i + 3] = q.w;
        }
    } else {
#pragma unroll
        for (int i = 0; i < CH; ++i) {
            int idx = base + i;
            loc[i] = (idx < N_NODES) ? deg[idx] : 0;
        }
    }
    int sum = 0;
#pragma unroll
    for (int i = 0; i < CH; ++i) sum += loc[i];
    s[t] = sum;
    __syncthreads();
    for (int off = 1; off < 1024; off <<= 1) {
        int v = (t >= off) ? s[t - off] : 0;
        __syncthreads();
        s[t] += v;
        __syncthreads();
    }
    int run = s[t] - sum;
#pragma unroll
    for (int i = 0; i < CH; ++i) {
        int idx = base + i;
        if (idx < N_NODES) {
            rowptr[idx] = run;
            cursor[idx] = run;
            run += loc[i];
        }
    }
    if (t == 1023) rowptr[N_NODES] = s[1023];
}

__global__ __launch_bounds__(256) void k_fill(const int* __restrict__ src,
                                              const int* __restrict__ dst,
                                              int* __restrict__ cursor,
                                              int* __restrict__ csr_src) {
    int i = blockIdx.x * 256 + threadIdx.x;
    if (i < N_EDGES) {
        int d = dst[i];
        int pos = atomicAdd(&cursor[d], 1);
        csr_src[pos] = src[i];
    }
}

// ---------------- GEMM: ft = X*Wfc^T, res = X*Wres^T (swapped-operand MFMA) ----------------
// mfma(w_frag, h_frag): D col(lane&15) = node row, D reg row = output col.
// Per lane: node r = r0+(lane&15); cols = nt*16 + (lane>>4)*4 + j  -> 4 consecutive
// cols per f32x4 acc -> packed 8B bf16x4 stores. attn dot per-lane over its 16 cols,
// reduced with 2 shfl_xor (16,32).
__global__ __launch_bounds__(256) void k_gemm(
    const float* __restrict__ h,
    const bf16_t* __restrict__ wfb,
    const bf16_t* __restrict__ wrb,
    const float* __restrict__ attl,
    const float* __restrict__ attr,
    bf16_t* __restrict__ ft,
    bf16_t* __restrict__ resb,
    float* __restrict__ al,
    float* __restrict__ ar)
{
    int wid  = (blockIdx.x * blockDim.x + threadIdx.x) >> 6;
    if (wid >= ROW_TILES) return;
    int lane = threadIdx.x & 63;
    int lr = lane & 15, lg = lane >> 4;
    int r0 = wid << 4;

    const f32x4*  hv = reinterpret_cast<const f32x4*>(h);
    const bf16x8* wf = reinterpret_cast<const bf16x8*>(wfb);
    const bf16x8* wr = reinterpret_cast<const bf16x8*>(wrb);

    // h fragment: row r0+lr, k = lg*8 + i (+32 for a1)
    int abase = (r0 + lr) * 16 + lg * 2;              // f32x4 units
    bf16x8 a0 = cvt8(hv[abase + 0], hv[abase + 1]);
    bf16x8 a1 = cvt8(hv[abase + 8], hv[abase + 9]);

    f32x4 dfc[4], dre[4];
#pragma unroll
    for (int nt = 0; nt < 4; ++nt) {
        int brow = (nt * 16 + lr) * 8;                // bf16x8 units per 64-elem row
        f32x4 z = {0.f, 0.f, 0.f, 0.f};
        z = __builtin_amdgcn_mfma_f32_16x16x32_bf16(wf[brow + lg],     a0, z, 0, 0, 0);
        z = __builtin_amdgcn_mfma_f32_16x16x32_bf16(wf[brow + 4 + lg], a1, z, 0, 0, 0);
        dfc[nt] = z;
        f32x4 y = {0.f, 0.f, 0.f, 0.f};
        y = __builtin_amdgcn_mfma_f32_16x16x32_bf16(wr[brow + lg],     a0, y, 0, 0, 0);
        y = __builtin_amdgcn_mfma_f32_16x16x32_bf16(wr[brow + 4 + lg], a1, y, 0, 0, 0);
        dre[nt] = y;
    }

    int r  = r0 + lr;           // this lane's node row
    int hh = r % NHEAD;
    float pl = 0.f, pr = 0.f;
#pragma unroll
    for (int nt = 0; nt < 4; ++nt) {
        bf16x4 pf, pe;
#pragma unroll
        for (int j = 0; j < 4; ++j) {
            int c = nt * 16 + lg * 4 + j;
            float vf = dfc[nt][j];
            pl += vf * attl[hh * 64 + c];
            pr += vf * attr[hh * 64 + c];
            pf[j] = (bf16_t)vf;
            pe[j] = (bf16_t)dre[nt][j];
        }
        *reinterpret_cast<bf16x4*>(ft   + r * 64 + nt * 16 + lg * 4) = pf;
        *reinterpret_cast<bf16x4*>(resb + r * 64 + nt * 16 + lg * 4) = pe;
    }
    // reduce across the 4 lg-groups (bits 4,5 of lane)
    pl += __shfl_xor(pl, 16); pl += __shfl_xor(pl, 32);
    pr += __shfl_xor(pr, 16); pr += __shfl_xor(pr, 32);
    if (lane < 16) {
        al[r0 + lane] = pl;
        ar[r0 + lane] = pr;
    }
}

// ---------------- softmax + aggregate + residual + relu ----------------
// One BLOCK (768 thr = 12 waves) per dst node; wave = head, lane = feature.
// All 12 heads read each edge's ft row simultaneously -> one contiguous 1536B
// burst per edge instead of 12 temporally-scattered 128B line requests.
#define ABATCH 4
__global__ __launch_bounds__(768) void k_agg(
    const int* __restrict__ rowptr, const int* __restrict__ csr_src,
    const float* __restrict__ al, const float* __restrict__ ar,
    const bf16_t* __restrict__ ft, const bf16_t* __restrict__ resb,
    float* __restrict__ out)
{
    int d0   = blockIdx.x;
    int hh   = threadIdx.x >> 6;
    int lane = threadIdx.x & 63;
    int beg = rowptr[d0], end = rowptr[d0 + 1];
    int row = d0 * NHEAD + hh;
    float r   = (float)resb[row * 64 + lane];
    float ard = ar[row];
    float acc = 0.f, den = 0.f;
    for (int j0 = beg; j0 < end; j0 += ABATCH) {
        int idx[ABATCH]; float w[ABATCH], v[ABATCH];
#pragma unroll
        for (int u = 0; u < ABATCH; ++u) {
            int j = j0 + u;
            idx[u] = (j < end) ? csr_src[j] : -1;
        }
#pragma unroll
        for (int u = 0; u < ABATCH; ++u)
            v[u] = (idx[u] >= 0) ? (float)ft[idx[u] * 768 + hh * 64 + lane] : 0.f;
#pragma unroll
        for (int u = 0; u < ABATCH; ++u) {
            if (idx[u] >= 0) {
                float e = al[idx[u] * NHEAD + hh] + ard;
                e = (e > 0.f) ? e : 0.2f * e;          // leaky_relu
                w[u] = __expf(e);
            } else w[u] = 0.f;
        }
#pragma unroll
        for (int u = 0; u < ABATCH; ++u) { den += w[u]; acc += w[u] * v[u]; }
    }
    float o = r + acc / den;
    __builtin_nontemporal_store(o > 0.f ? o : 0.f, &out[row * 64 + lane]);
}

extern "C" void kernel_launch(void* const* d_in, const int* in_sizes, int n_in,
                              void* d_out, int out_size, void* d_ws, size_t ws_size,
                              hipStream_t stream) {
    const float* h    = (const float*)d_in[0];
    const float* wfc  = (const float*)d_in[1];
    const float* attl = (const float*)d_in[2];
    const float* attr = (const float*)d_in[3];
    const float* wres = (const float*)d_in[4];
    const int*   src  = (const int*)d_in[5];
    const int*   dst  = (const int*)d_in[6];
    float* out = (float*)d_out;

    char* ws = (char*)d_ws;
    bf16_t* ft     = (bf16_t*)(ws + 0);          //  76,800,000 B
    bf16_t* resb   = (bf16_t*)(ws + 76800000);   //  76,800,000 B
    float*  al     = (float*)(ws + 153600000);   //   2,400,000 B
    float*  ar     = (float*)(ws + 156000000);   //   2,400,000 B
    int*    deg    = (int*)(ws + 158400000);     //     200,448 B
    int*    rowptr = (int*)(ws + 158600448);     //     200,448 B
    int*    cursor = (int*)(ws + 158800896);     //     200,448 B
    int*    csrsrc = (int*)(ws + 159001344);     //   1,000,000 B
    bf16_t* wfb    = (bf16_t*)(ws + 160001344);  //       8,192 B
    bf16_t* wrb    = (bf16_t*)(ws + 160009536);  //       8,192 B  (end ~160.02 MB)

    hipMemsetAsync(deg, 0, N_NODES * sizeof(int), stream);
    k_deg_prep<<<993, 256, 0, stream>>>(dst, deg, wfc, wres, wfb, wrb);
    k_scan<<<1, 1024, 0, stream>>>(deg, rowptr, cursor);
    k_fill<<<977, 256, 0, stream>>>(src, dst, cursor, csrsrc);
    k_gemm<<<ROW_TILES / 4, 256, 0, stream>>>(h, wfb, wrb, attl, attr, ft, resb, al, ar);
    k_agg<<<N_NODES, 768, 0, stream>>>(rowptr, csrsrc, al, ar, ft, resb, out);
}

// Round 5
// 480.806 us; speedup vs baseline: 1.3117x; 1.3117x over previous
//
#include <hip/hip_runtime.h>
#include <hip/hip_bf16.h>

#define N_NODES 50000
#define N_EDGES 250000
#define NHEAD   12
#define NH      (N_NODES * NHEAD)   /* 600000 rows of 64 */
#define ROW_TILES (NH / 16)         /* 37500 */

typedef __bf16 bf16_t;
typedef __bf16 bf16x8 __attribute__((ext_vector_type(8)));
typedef __bf16 bf16x4 __attribute__((ext_vector_type(4)));
typedef float  f32x4  __attribute__((ext_vector_type(4)));

__device__ __forceinline__ bf16x8 cvt8(f32x4 a, f32x4 b) {
    bf16x8 r;
    r[0] = (bf16_t)a[0]; r[1] = (bf16_t)a[1]; r[2] = (bf16_t)a[2]; r[3] = (bf16_t)a[3];
    r[4] = (bf16_t)b[0]; r[5] = (bf16_t)b[1]; r[6] = (bf16_t)b[2]; r[7] = (bf16_t)b[3];
    return r;
}

// ---------------- degree histogram + weight bf16 pre-conversion ----------------
__global__ __launch_bounds__(256) void k_deg_prep(
    const int* __restrict__ dst, int* __restrict__ deg,
    const float* __restrict__ wfc, const float* __restrict__ wres,
    bf16_t* __restrict__ wfb, bf16_t* __restrict__ wrb)
{
    int b = blockIdx.x;
    if (b < 977) {
        int i = b * 256 + threadIdx.x;
        if (i < N_EDGES) atomicAdd(&deg[dst[i]], 1);
    } else {
        int t = (b - 977) * 256 + threadIdx.x;   // 0..4095
        wfb[t] = (bf16_t)wfc[t];
        wrb[t] = (bf16_t)wres[t];
    }
}

// single block, 1024 threads, 52 nodes/thread; int4-vectorized loads.
__global__ __launch_bounds__(1024) void k_scan(const int* __restrict__ deg,
                                               int* __restrict__ rowptr,
                                               int* __restrict__ cursor) {
    __shared__ int s[1024];
    const int CH = 52;
    int t = threadIdx.x;
    int base = t * CH;
    int loc[CH];
    if (base + CH <= N_NODES) {
        const int4* p = reinterpret_cast<const int4*>(deg + base);
#pragma unroll
        for (int i = 0; i < CH / 4; ++i) {
            int4 q = p[i];
            loc[4 * i + 0] = q.x; loc[4 * i + 1] = q.y;
            loc[4 * i + 2] = q.z; loc[4 * i + 3] = q.w;
        }
    } else {
#pragma unroll
        for (int i = 0; i < CH; ++i) {
            int idx = base + i;
            loc[i] = (idx < N_NODES) ? deg[idx] : 0;
        }
    }
    int sum = 0;
#pragma unroll
    for (int i = 0; i < CH; ++i) sum += loc[i];
    s[t] = sum;
    __syncthreads();
    for (int off = 1; off < 1024; off <<= 1) {
        int v = (t >= off) ? s[t - off] : 0;
        __syncthreads();
        s[t] += v;
        __syncthreads();
    }
    int run = s[t] - sum;
#pragma unroll
    for (int i = 0; i < CH; ++i) {
        int idx = base + i;
        if (idx < N_NODES) {
            rowptr[idx] = run;
            cursor[idx] = run;
            run += loc[i];
        }
    }
    if (t == 1023) rowptr[N_NODES] = s[1023];
}

// CSR fill; also records csrdst so later passes are CSR-ordered.
__global__ __launch_bounds__(256) void k_fill(const int* __restrict__ src,
                                              const int* __restrict__ dst,
                                              int* __restrict__ cursor,
                                              int* __restrict__ csr_src,
                                              int* __restrict__ csr_dst) {
    int i = blockIdx.x * 256 + threadIdx.x;
    if (i < N_EDGES) {
        int d = dst[i];
        int pos = atomicAdd(&cursor[d], 1);
        csr_src[pos] = src[i];
        csr_dst[pos] = d;
    }
}

// ---------------- GEMM: ft = X*Wfc^T, res = X*Wres^T (swapped-operand MFMA) ----------------
__global__ __launch_bounds__(256) void k_gemm(
    const float* __restrict__ h,
    const bf16_t* __restrict__ wfb,
    const bf16_t* __restrict__ wrb,
    const float* __restrict__ attl,
    const float* __restrict__ attr,
    bf16_t* __restrict__ ft,
    bf16_t* __restrict__ resb,
    float* __restrict__ al,
    float* __restrict__ ar)
{
    int wid  = (blockIdx.x * blockDim.x + threadIdx.x) >> 6;
    if (wid >= ROW_TILES) return;
    int lane = threadIdx.x & 63;
    int lr = lane & 15, lg = lane >> 4;
    int r0 = wid << 4;

    const f32x4*  hv = reinterpret_cast<const f32x4*>(h);
    const bf16x8* wf = reinterpret_cast<const bf16x8*>(wfb);
    const bf16x8* wr = reinterpret_cast<const bf16x8*>(wrb);

    int abase = (r0 + lr) * 16 + lg * 2;              // f32x4 units
    bf16x8 a0 = cvt8(hv[abase + 0], hv[abase + 1]);
    bf16x8 a1 = cvt8(hv[abase + 8], hv[abase + 9]);

    f32x4 dfc[4], dre[4];
#pragma unroll
    for (int nt = 0; nt < 4; ++nt) {
        int brow = (nt * 16 + lr) * 8;                // bf16x8 units per 64-elem row
        f32x4 z = {0.f, 0.f, 0.f, 0.f};
        z = __builtin_amdgcn_mfma_f32_16x16x32_bf16(wf[brow + lg],     a0, z, 0, 0, 0);
        z = __builtin_amdgcn_mfma_f32_16x16x32_bf16(wf[brow + 4 + lg], a1, z, 0, 0, 0);
        dfc[nt] = z;
        f32x4 y = {0.f, 0.f, 0.f, 0.f};
        y = __builtin_amdgcn_mfma_f32_16x16x32_bf16(wr[brow + lg],     a0, y, 0, 0, 0);
        y = __builtin_amdgcn_mfma_f32_16x16x32_bf16(wr[brow + 4 + lg], a1, y, 0, 0, 0);
        dre[nt] = y;
    }

    int r  = r0 + lr;           // this lane's node row
    int hh = r % NHEAD;
    float pl = 0.f, pr = 0.f;
#pragma unroll
    for (int nt = 0; nt < 4; ++nt) {
        bf16x4 pf, pe;
#pragma unroll
        for (int j = 0; j < 4; ++j) {
            int c = nt * 16 + lg * 4 + j;
            float vf = dfc[nt][j];
            pl += vf * attl[hh * 64 + c];
            pr += vf * attr[hh * 64 + c];
            pf[j] = (bf16_t)vf;
            pe[j] = (bf16_t)dre[nt][j];
        }
        *reinterpret_cast<bf16x4*>(ft   + r * 64 + nt * 16 + lg * 4) = pf;
        *reinterpret_cast<bf16x4*>(resb + r * 64 + nt * 16 + lg * 4) = pe;
    }
    pl += __shfl_xor(pl, 16); pl += __shfl_xor(pl, 32);
    pr += __shfl_xor(pr, 16); pr += __shfl_xor(pr, 32);
    if (lane < 16) {
        al[r0 + lane] = pl;
        ar[r0 + lane] = pr;
    }
}

// ---------------- per-edge softmax weights, all 12 heads, CSR order ----------------
// Thread = one CSR edge position. al/ar are 2.4MB L2-resident tables read as
// 3x float4 (48B, 16B-aligned since 12 floats = 48B). Writes w[h][p] transposed:
// per wave each h-row write is 64 contiguous floats -> coalesced.
__global__ __launch_bounds__(256) void k_edgew(
    const int* __restrict__ csr_src, const int* __restrict__ csr_dst,
    const float* __restrict__ al, const float* __restrict__ ar,
    float* __restrict__ w)
{
    int e = blockIdx.x * 256 + threadIdx.x;
    if (e >= N_EDGES) return;
    int s = csr_src[e], d = csr_dst[e];
    const f32x4* ap = reinterpret_cast<const f32x4*>(al + s * NHEAD);
    const f32x4* bp = reinterpret_cast<const f32x4*>(ar + d * NHEAD);
#pragma unroll
    for (int q = 0; q < 3; ++q) {
        f32x4 a = ap[q], b = bp[q];
#pragma unroll
        for (int j = 0; j < 4; ++j) {
            float x = a[j] + b[j];
            x = (x > 0.f) ? x : 0.2f * x;          // leaky_relu
            w[(q * 4 + j) * N_EDGES + e] = __expf(x);
        }
    }
}

// ---------------- softmax-normalize + aggregate + residual + relu ----------------
// Wave per (dst,head); lane = feature. Only ONE random-gather level remains (ft);
// weights come in as a contiguous f32 run per segment.
#define DB 8
__global__ __launch_bounds__(256) void k_agg(
    const int* __restrict__ rowptr, const int* __restrict__ csr_src,
    const float* __restrict__ w,
    const bf16_t* __restrict__ ft, const bf16_t* __restrict__ resb,
    float* __restrict__ out)
{
    int wid = (blockIdx.x * 256 + threadIdx.x) >> 6;
    if (wid >= NH) return;
    int lane = threadIdx.x & 63;
    int d0 = wid / NHEAD;
    int hh = wid - d0 * NHEAD;
    int beg = rowptr[d0], end = rowptr[d0 + 1];
    float r = (float)__builtin_nontemporal_load(&resb[wid * 64 + lane]);
    const float* wrow = w + hh * N_EDGES;
    float acc = 0.f, den = 0.f;
    for (int j0 = beg; j0 < end; j0 += DB) {
        int idx[DB]; float wv[DB], v[DB];
#pragma unroll
        for (int u = 0; u < DB; ++u) {
            int j = j0 + u;
            idx[u] = (j < end) ? csr_src[j] : -1;
        }
#pragma unroll
        for (int u = 0; u < DB; ++u)
            wv[u] = (idx[u] >= 0) ? wrow[j0 + u] : 0.f;
#pragma unroll
        for (int u = 0; u < DB; ++u)
            v[u] = (idx[u] >= 0) ? (float)ft[idx[u] * 768 + hh * 64 + lane] : 0.f;
#pragma unroll
        for (int u = 0; u < DB; ++u) { den += wv[u]; acc += wv[u] * v[u]; }
    }
    float o = r + acc / den;
    __builtin_nontemporal_store(o > 0.f ? o : 0.f, &out[wid * 64 + lane]);
}

extern "C" void kernel_launch(void* const* d_in, const int* in_sizes, int n_in,
                              void* d_out, int out_size, void* d_ws, size_t ws_size,
                              hipStream_t stream) {
    const float* h    = (const float*)d_in[0];
    const float* wfc  = (const float*)d_in[1];
    const float* attl = (const float*)d_in[2];
    const float* attr = (const float*)d_in[3];
    const float* wres = (const float*)d_in[4];
    const int*   src  = (const int*)d_in[5];
    const int*   dst  = (const int*)d_in[6];
    float* out = (float*)d_out;

    char* ws = (char*)d_ws;
    bf16_t* ft     = (bf16_t*)(ws + 0);          //  76,800,000 B
    bf16_t* resb   = (bf16_t*)(ws + 76800000);   //  76,800,000 B
    float*  al     = (float*)(ws + 153600000);   //   2,400,000 B
    float*  ar     = (float*)(ws + 156000000);   //   2,400,000 B
    int*    deg    = (int*)(ws + 158400000);     //     200,448 B
    int*    rowptr = (int*)(ws + 158600448);     //     200,448 B
    int*    cursor = (int*)(ws + 158800896);     //     200,448 B
    int*    csrsrc = (int*)(ws + 159001344);     //   1,000,000 B
    int*    csrdst = (int*)(ws + 160001344);     //   1,000,000 B
    bf16_t* wfb    = (bf16_t*)(ws + 161001344);  //       8,192 B
    bf16_t* wrb    = (bf16_t*)(ws + 161009536);  //       8,192 B
    float*  wbuf   = (float*)(ws + 161017728);   //  12,000,000 B (end ~173 MB)

    hipMemsetAsync(deg, 0, N_NODES * sizeof(int), stream);
    k_deg_prep<<<993, 256, 0, stream>>>(dst, deg, wfc, wres, wfb, wrb);
    k_scan<<<1, 1024, 0, stream>>>(deg, rowptr, cursor);
    k_fill<<<977, 256, 0, stream>>>(src, dst, cursor, csrsrc, csrdst);
    k_gemm<<<ROW_TILES / 4, 256, 0, stream>>>(h, wfb, wrb, attl, attr, ft, resb, al, ar);
    k_edgew<<<977, 256, 0, stream>>>(csrsrc, csrdst, al, ar, wbuf);
    k_agg<<<NH / 4, 256, 0, stream>>>(rowptr, csrsrc, wbuf, ft, resb, out);
}